// Round 16
// baseline (121.307 us; speedup 1.0000x reference)
//
#include <hip/hip_runtime.h>

#define VV 6890
#define N3 20670      // V*3
#define NVT 216       // ceil(N3/96) vertex tiles (32 verts each)
#define NKC 7         // K chunks of 32 (K=224)
#define NJOUT 61
#define OUTJ ((size_t)1024*VV*3)
#define NJCH 216      // ceil(VV/32) v-chunks for joint regression
#define NSEG 27       // split-K segments for joint regression (216 = 27*8)

// ws layout (bytes): JT f32[72]@0, JS f32[720]@288, JallF bf16 @4096 (432KB),
// Ablk bf16 @1183744, Bblk bf16 @1642496 (9.29MB; REUSED as jreg partials after
// k_fused), A2 @10932224, W2 @12505088 -> total 12947456 (proven footprint)
#define WS_JT 0
#define WS_JS 72
#define WS_JALL_BYTES 4096
#define WS_ABLK_BYTES 1183744
#define WS_BBLK_BYTES 1642496
#define WS_A2_BYTES   10932224
#define WS_W2_BYTES   12505088

typedef float f32x4 __attribute__((ext_vector_type(4)));
typedef short bf16x8 __attribute__((ext_vector_type(8)));

__constant__ int c_par[24] = {-1,0,0,0,1,2,3,4,5,6,7,8,9,9,9,12,13,14,16,17,18,19,20,21};

__device__ __forceinline__ short f2bf(float x) {
    union { float f; unsigned u; } v; v.f = x;
    unsigned r = (v.u + 0x7fffu + ((v.u >> 16) & 1u)) >> 16;
    return (short)r;
}
__device__ __forceinline__ float bf2f(short h) {
    union { unsigned u; float f; } v; v.u = ((unsigned)(unsigned short)h) << 16;
    return v.f;
}

// ---- K0: merged prep. bid<1512: buildB tile; <1944: W2/JallF frags; <2016: jointreg ----
__global__ __launch_bounds__(256) void k_prep(
    const float* __restrict__ pd, const float* __restrict__ sd,
    const float* __restrict__ lbsw, const float* __restrict__ Je9,
    const float* __restrict__ Jh, const float* __restrict__ Jreg,
    const float* __restrict__ vt,
    short* __restrict__ Bblk, short* __restrict__ W2, short* __restrict__ JallF,
    float* __restrict__ ws)
{
    const int bid = blockIdx.x;
    const int tid = threadIdx.x;
    __shared__ float T[32][97];

    if (bid < 1512) {
        const int nt = bid / 7, kc = bid % 7;
        for (int idx = tid; idx < 3072; idx += 256) {
            const int kl = idx / 96, c = idx % 96;
            const int kg = kc*32 + kl;
            const int n = nt*96 + c;
            float val = 0.f;
            if (n < N3) {
                if (kg < 207) val = pd[(size_t)kg*N3 + n];
                else if (kg < 217) val = sd[(size_t)(n/3)*30 + (n%3)*10 + (kg-207)];
            }
            T[kl][c] = val;
        }
        __syncthreads();
        short* tile = Bblk + (size_t)(nt*NKC + kc)*3072;
        for (int s = tid; s < 384; s += 256) {
            const int c = s >> 2;
            const int hi = (s & 3) ^ ((c >> 1) & 3);
            bf16x8 pk;
#pragma unroll
            for (int e = 0; e < 8; e++) pk[e] = f2bf(T[hi*8+e][c]);
            *(bf16x8*)(tile + s*8) = pk;
        }
    } else if (bid < 1944) {
        if (tid < 64) {
            const int l = tid;
            const int l15 = l & 15, l4 = l >> 4;
            const int sb = bid - 1512;
            if (sb < NVT) {
                const int nt = sb;
#pragma unroll
                for (int nh = 0; nh < 2; nh++) {
                    const int v = nt*32 + nh*16 + l15;
                    bf16x8 pk;
#pragma unroll
                    for (int q = 0; q < 8; q++) {
                        const int j = l4*8 + q;
                        float val = (j < 24 && v < VV) ? lbsw[(size_t)v*24 + j] : 0.f;
                        pk[q] = f2bf(val);
                    }
                    *(bf16x8*)(W2 + ((size_t)(nt*2 + nh)*512) + l*8) = pk;
                }
            } else {
                const int ch = sb - NVT;
#pragma unroll
                for (int jh = 0; jh < 2; jh++) {
                    const int j = jh*16 + l15;
                    bf16x8 pk;
#pragma unroll
                    for (int q = 0; q < 8; q++) {
                        const int v = ch*32 + l4*8 + q;
                        float val = 0.f;
                        if (j < 26 && v < VV)
                            val = (j < 9) ? Je9[(size_t)j*VV + v] : Jh[(size_t)(j-9)*VV + v];
                        pk[q] = f2bf(val);
                    }
                    *(bf16x8*)(JallF + ((size_t)ch*2 + jh)*512 + l*8) = pk;
                }
            }
        }
    } else {
        const int jb = bid - 1944;
        const int j = jb / 3, k = jb % 3;
        float acc[11];
#pragma unroll
        for (int i = 0; i < 11; i++) acc[i] = 0.f;
        for (int v = tid; v < VV; v += 256) {
            const float jr = Jreg[j*VV + v];
            acc[0] += jr * vt[v*3 + k];
            const float* s = sd + (size_t)v*30 + k*10;
#pragma unroll
            for (int l = 0; l < 10; l++) acc[1+l] += jr * s[l];
        }
#pragma unroll
        for (int off = 1; off < 64; off <<= 1)
#pragma unroll
            for (int i = 0; i < 11; i++) acc[i] += __shfl_xor(acc[i], off);
        const int wv = tid >> 6, ln = tid & 63;
        if (ln == 0)
#pragma unroll
            for (int i = 0; i < 11; i++) T[wv][i] = acc[i];
        __syncthreads();
        if (tid == 0) {
            ws[WS_JT + j*3 + k] = T[0][0]+T[1][0]+T[2][0]+T[3][0];
#pragma unroll
            for (int l = 0; l < 10; l++)
                ws[WS_JS + (j*3+k)*10 + l] = T[0][1+l]+T[1][1+l]+T[2][1+l]+T[3][1+l];
        }
    }
}

// ---- K1: rodrigues + chain + bf16 A-matrix + A2 hi/lo fragments + joints[0:24] ----
__global__ __launch_bounds__(64) void k_batch(
    const float* __restrict__ betas, const float* __restrict__ poses,
    float* __restrict__ ws, short* __restrict__ Ablk, short* __restrict__ A2,
    float* __restrict__ out)
{
    const int b = blockIdx.x, lane = threadIdx.x;
    __shared__ float R[24][9], Jr[24][3], RJ[24][3], G[24][12];
    if (lane < 24) {
        const int j = lane;
        const float x = poses[b*72 + j*3 + 0];
        const float y = poses[b*72 + j*3 + 1];
        const float z = poses[b*72 + j*3 + 2];
        const float xe = x + 1e-8f, ye = y + 1e-8f, ze = z + 1e-8f;
        const float ang = sqrtf(xe*xe + ye*ye + ze*ze);
        const float inv = 1.0f / ang;
        const float rx = x*inv, ry = y*inv, rz = z*inv;
        const float sn = sinf(ang), cs = cosf(ang);
        const float K[9] = {0.f,-rz,ry, rz,0.f,-rx, -ry,rx,0.f};
        float Rl[9];
#pragma unroll
        for (int r = 0; r < 3; r++)
#pragma unroll
            for (int c = 0; c < 3; c++) {
                float kk = 0.f;
#pragma unroll
                for (int m = 0; m < 3; m++) kk += K[r*3+m]*K[m*3+c];
                Rl[r*3+c] = ((r==c)?1.f:0.f) + sn*K[r*3+c] + (1.f-cs)*kk;
            }
#pragma unroll
        for (int e = 0; e < 9; e++) R[j][e] = Rl[e];
#pragma unroll
        for (int k = 0; k < 3; k++) {
            float a = ws[WS_JT + j*3 + k];
#pragma unroll
            for (int l = 0; l < 10; l++) a += betas[b*10 + l] * ws[WS_JS + (j*3+k)*10 + l];
            Jr[j][k] = a;
        }
    }
    __syncthreads();
    {
        const int r = b & 31, mt = b >> 5;
        const int sw = (r >> 1) & 3;
        for (int k = lane; k < 224; k += 64) {
            float val;
            if (k < 207) { const int j = k/9 + 1, e = k - (j-1)*9;
                           val = R[j][e] - ((e==0||e==4||e==8)?1.f:0.f); }
            else if (k < 217) val = betas[b*10 + (k-207)];
            else val = 0.f;
            const int kc = k >> 5, hi = (k >> 3) & 3;
            Ablk[(size_t)(mt*NKC + kc)*1024 + r*32 + ((hi ^ sw)*8) + (k & 7)] = f2bf(val);
        }
    }
    if (lane < 24) {
        const int j = lane, p = c_par[j];
#pragma unroll
        for (int k = 0; k < 3; k++) RJ[j][k] = (j == 0) ? Jr[0][k] : (Jr[j][k] - Jr[p][k]);
    }
    __syncthreads();
    if (lane < 12) {
        const int r = lane >> 2, c = lane & 3;
        G[0][lane] = (c < 3) ? R[0][r*3+c] : RJ[0][r];
    }
    __syncthreads();
    for (int i = 1; i < 24; i++) {
        float val = 0.f;
        if (lane < 12) {
            const int r = lane >> 2, c = lane & 3, p = c_par[i];
            if (c < 3)
                val = G[p][r*4+0]*R[i][0+c] + G[p][r*4+1]*R[i][3+c] + G[p][r*4+2]*R[i][6+c];
            else
                val = G[p][r*4+0]*RJ[i][0] + G[p][r*4+1]*RJ[i][1] + G[p][r*4+2]*RJ[i][2] + G[p][r*4+3];
        }
        __syncthreads();
        if (lane < 12) G[i][lane] = val;
        __syncthreads();
    }
    if (lane < 24)
#pragma unroll
        for (int k = 0; k < 3; k++)
            out[OUTJ + ((size_t)b*NJOUT + lane)*3 + k] = G[lane][k*4+3];
    const int bt = b >> 5, mh = (b >> 4) & 1, b15 = b & 15;
    short* A2t = A2 + (size_t)bt*12*2*2*512;
    for (int e = lane; e < 288; e += 64) {
        const int j = e / 12, rc = e % 12, r = rc >> 2, c = rc & 3;
        float val = G[j][rc];
        if (c == 3)
            val -= G[j][r*4+0]*Jr[j][0] + G[j][r*4+1]*Jr[j][1] + G[j][r*4+2]*Jr[j][2];
        const short vhi = f2bf(val);
        const short vlo = f2bf(val - bf2f(vhi));
        const int lf = (j >> 3)*16 + b15, q = j & 7;
        A2t[((rc*2 + 0)*2 + mh)*512 + lf*8 + q] = vhi;
        A2t[((rc*2 + 1)*2 + mh)*512 + lf*8 + q] = vlo;
    }
    for (int idx = lane; idx < 192; idx += 64) {
        const int rc = idx >> 4, spl = (idx >> 3) & 1, q = idx & 7;
        A2t[((rc*2 + spl)*2 + mh)*512 + (48 + b15)*8 + q] = 0;
    }
}

// ---- K2: FUSED, 2-nt tile (32 b x 64 v). a2f/af loads amortized across both nt
//      (A2 is nt-independent). Tl16 reused sequentially nt0 -> nt1.
//      LDS = 25088 + 2*16896 = 58880 -> 2 blocks/CU. ----
__global__ __launch_bounds__(256, 2) void k_fused(
    const short* __restrict__ Ablk, const short* __restrict__ Bblk,
    const short* __restrict__ A2, const short* __restrict__ W2,
    const float* __restrict__ vt, float* __restrict__ out)
{
    const int nt0 = blockIdx.x*2, nt1 = nt0 + 1;
    const int bt = blockIdx.y;
    const int tid = threadIdx.x;
    const int lane = tid & 63, wid = tid >> 6;
    const int wm = wid >> 1, wn = wid & 1;
    const int l15 = lane & 15, l4 = lane >> 4;

    __shared__ char SM[58880] __attribute__((aligned(16)));
    float*  Tl16 = (float*)SM;            // [32 b][12 e][16 v] stride 196 = 25088 B
    float*  vp0  = (float*)(SM + 25088);  // [32 b][132] = 16896 B
    float*  vp1  = (float*)(SM + 41984);  // [32 b][132] = 16896 B

    // ---- early fragments: a2f (nt-independent), w2f per nt ----
    const int e_base = wid*3;
    bf16x8 a2f[3][2][2], w2f0[2], w2f1[2];
    {
        const short* A2t = A2 + (size_t)bt*12*2*2*512;
#pragma unroll
        for (int ee = 0; ee < 3; ee++)
#pragma unroll
            for (int mh = 0; mh < 2; mh++)
#pragma unroll
                for (int spl = 0; spl < 2; spl++)
                    a2f[ee][mh][spl] = *(const bf16x8*)(A2t + (((e_base+ee)*2 + spl)*2 + mh)*512 + lane*8);
#pragma unroll
        for (int nh = 0; nh < 2; nh++) {
            w2f0[nh] = *(const bf16x8*)(W2 + (size_t)(nt0*2 + nh)*512 + lane*8);
            w2f1[nh] = *(const bf16x8*)(W2 + (size_t)(nt1*2 + nh)*512 + lane*8);
        }
    }

    // ---- phase 1: pose GEMM for both nt, fragments direct from global ----
    f32x4 acc0[3], acc1[3];
#pragma unroll
    for (int n = 0; n < 3; n++) {
        acc0[n] = (f32x4){0.f,0.f,0.f,0.f};
        acc1[n] = (f32x4){0.f,0.f,0.f,0.f};
    }
    const int ar = wm*16 + l15;
    const int aoff = ar*32 + ((l4 ^ ((ar >> 1) & 3)) * 8);
    int boff[3];
#pragma unroll
    for (int n = 0; n < 3; n++) {
        const int c = wn*48 + n*16 + l15;
        boff[n] = c*32 + ((l4 ^ ((c >> 1) & 3)) * 8);
    }
    const short* gA  = Ablk + (size_t)bt*NKC*1024;
    const short* gB0 = Bblk + (size_t)nt0*NKC*3072;
    const short* gB1 = Bblk + (size_t)nt1*NKC*3072;

#pragma unroll
    for (int kc = 0; kc < NKC; kc++) {
        const bf16x8 af = *(const bf16x8*)(gA + kc*1024 + aoff);
#pragma unroll
        for (int n = 0; n < 3; n++) {
            const bf16x8 b0 = *(const bf16x8*)(gB0 + kc*3072 + boff[n]);
            acc0[n] = __builtin_amdgcn_mfma_f32_16x16x32_bf16(af, b0, acc0[n], 0, 0, 0);
        }
#pragma unroll
        for (int n = 0; n < 3; n++) {
            const bf16x8 b1 = *(const bf16x8*)(gB1 + kc*3072 + boff[n]);
            acc1[n] = __builtin_amdgcn_mfma_f32_16x16x32_bf16(af, b1, acc1[n], 0, 0, 0);
        }
    }

    // ---- phase 2: acc + v_template -> vp0 / vp1 (stride 132) ----
#pragma unroll
    for (int n = 0; n < 3; n++) {
        const int cl = wn*48 + n*16 + l15;
        const int vloc = cl / 3, kk = cl - vloc*3;
        const int b0 = wm*16 + l4*4;
        {
            const int cg = nt0*96 + cl;
            const float vtv = (cg < N3) ? vt[cg] : 0.f;
#pragma unroll
            for (int rg = 0; rg < 4; rg++)
                vp0[(b0+rg)*132 + vloc*4 + kk] = acc0[n][rg] + vtv;
        }
        {
            const int cg = nt1*96 + cl;
            const float vtv = (cg < N3) ? vt[cg] : 0.f;
#pragma unroll
            for (int rg = 0; rg < 4; rg++)
                vp1[(b0+rg)*132 + vloc*4 + kk] = acc1[n][rg] + vtv;
        }
    }

    // ---- phases 3+4 per nt: T via MFMA (registers), Tl16 halves, consume ----
#pragma unroll
    for (int part = 0; part < 2; part++) {
        const int nt = part ? nt1 : nt0;
        const float* vp = part ? vp1 : vp0;
        f32x4 at[3][2][2];
#pragma unroll
        for (int ee = 0; ee < 3; ee++)
#pragma unroll
            for (int mh = 0; mh < 2; mh++)
#pragma unroll
                for (int nh = 0; nh < 2; nh++) {
                    const bf16x8 w = part ? w2f1[nh] : w2f0[nh];
                    f32x4 t = (f32x4){0.f,0.f,0.f,0.f};
                    t = __builtin_amdgcn_mfma_f32_16x16x32_bf16(a2f[ee][mh][0], w, t, 0, 0, 0);
                    t = __builtin_amdgcn_mfma_f32_16x16x32_bf16(a2f[ee][mh][1], w, t, 0, 0, 0);
                    at[ee][mh][nh] = t;
                }
#pragma unroll
        for (int half = 0; half < 2; half++) {
#pragma unroll
            for (int ee = 0; ee < 3; ee++)
#pragma unroll
                for (int mh = 0; mh < 2; mh++) {
                    const int brow = mh*16 + l4*4;
#pragma unroll
                    for (int rg = 0; rg < 4; rg++)
                        Tl16[(brow+rg)*196 + (e_base+ee)*16 + l15] = at[ee][mh][half][rg];
                }
            __syncthreads();
            const int bl = tid >> 3, vq = tid & 7;
            const int bg = bt*32 + bl;
#pragma unroll
            for (int i = 0; i < 2; i++) {
                const int v = vq + 8*i;
                const float4 u = *(const float4*)&vp[bl*132 + (half*16 + v)*4];
                float t[12];
#pragma unroll
                for (int e = 0; e < 12; e++) t[e] = Tl16[bl*196 + e*16 + v];
                const float r0 = t[0]*u.x + t[1]*u.y + t[2]*u.z  + t[3];
                const float r1 = t[4]*u.x + t[5]*u.y + t[6]*u.z  + t[7];
                const float r2 = t[8]*u.x + t[9]*u.y + t[10]*u.z + t[11];
                const int gv = nt*32 + half*16 + v;
                if (gv < VV) {
                    const size_t base = (size_t)bg*N3 + (size_t)gv*3;
                    out[base+0] = r0; out[base+1] = r1; out[base+2] = r2;
                }
            }
            if (!(part == 1 && half == 1)) __syncthreads();   // Tl16 rewritten next
        }
    }
}

// ---- K3: joint regression split-K MFMA GEMM -> per-block partials (NO atomics) ----
__global__ __launch_bounds__(256) void k_jreg2(
    const float* __restrict__ vsrc, const short* __restrict__ JallF,
    float* __restrict__ P)
{
    const int bt = blockIdx.x, seg = blockIdx.y;   // grid (32, 27)
    const int tid = threadIdx.x;
    const int lane = tid & 63, wid = tid >> 6;
    const int jh = wid >> 1, nh = wid & 1;
    const int l15 = lane & 15, l4 = lane >> 4;

    f32x4 C[3];
#pragma unroll
    for (int k = 0; k < 3; k++) C[k] = (f32x4){0.f,0.f,0.f,0.f};

    const int rowb = bt*32 + nh*16 + l15;
    const float* vrow = vsrc + (size_t)rowb*N3;
    const int c0 = seg*8, c1 = c0 + 8;
    for (int ch = c0; ch < c1; ch++) {
        const float* p = vrow + ch*96 + l4*24;
        float2 g[12];
#pragma unroll
        for (int t = 0; t < 12; t++) g[t] = *(const float2*)(p + t*2);
        const bf16x8 af = *(const bf16x8*)(JallF + ((size_t)ch*2 + jh)*512 + lane*8);
#pragma unroll
        for (int k = 0; k < 3; k++) {
            bf16x8 bf;
#pragma unroll
            for (int q = 0; q < 8; q++) {
                const int e = q*3 + k;
                bf[q] = f2bf((e & 1) ? g[e>>1].y : g[e>>1].x);
            }
            C[k] = __builtin_amdgcn_mfma_f32_16x16x32_bf16(af, bf, C[k], 0, 0, 0);
        }
    }
    float* Pp = P + (size_t)(seg*32 + bt)*2496 + (nh*16 + l15)*78;
#pragma unroll
    for (int k = 0; k < 3; k++)
#pragma unroll
        for (int rg = 0; rg < 4; rg++) {
            const int j = jh*16 + l4*4 + rg;
            if (j < 26) Pp[j*3 + k] = C[k][rg];
        }
}

// ---- K4: reduce partials -> joints 35..60, and 11 gathered extra joints ----
__global__ __launch_bounds__(256) void k_tail(
    const float* __restrict__ P, const int* __restrict__ eidx, float* __restrict__ out)
{
    const int gid = blockIdx.x*256 + threadIdx.x;
    if (gid < 79872) {                       // 1024*78 jfin elements
        const int b = gid / 78, r = gid % 78;
        float s = 0.f;
#pragma unroll
        for (int seg = 0; seg < NSEG; seg++)
            s += P[(size_t)(seg*32 + (b >> 5))*2496 + (b & 31)*78 + r];
        out[OUTJ + (size_t)b*183 + 105 + r] = s;
    } else if (gid < 79872 + 33792) {        // 1024*33 extra elements
        const int idx = gid - 79872;
        const int b = idx / 33, r = idx % 33, j = r / 3, k = r % 3;
        out[OUTJ + ((size_t)b*NJOUT + 24 + j)*3 + k] =
            out[(size_t)b*N3 + (size_t)eidx[j]*3 + k];
    }
}

extern "C" void kernel_launch(void* const* d_in, const int* in_sizes, int n_in,
                              void* d_out, int out_size, void* d_ws, size_t ws_size,
                              hipStream_t stream) {
    const float* betas = (const float*)d_in[0];
    const float* poses = (const float*)d_in[1];
    const int*   eidx  = (const int*)  d_in[2];
    const float* vt    = (const float*)d_in[3];
    const float* sd    = (const float*)d_in[4];
    const float* pd    = (const float*)d_in[5];
    const float* Jreg  = (const float*)d_in[6];
    const float* lbsw  = (const float*)d_in[7];
    const float* Je9   = (const float*)d_in[8];
    const float* Jh    = (const float*)d_in[9];
    float* out = (float*)d_out;
    float* ws  = (float*)d_ws;
    short* JallF = (short*)((char*)d_ws + WS_JALL_BYTES);
    short* Ablk  = (short*)((char*)d_ws + WS_ABLK_BYTES);
    short* Bblk  = (short*)((char*)d_ws + WS_BBLK_BYTES);
    short* A2    = (short*)((char*)d_ws + WS_A2_BYTES);
    short* W2    = (short*)((char*)d_ws + WS_W2_BYTES);
    float* Pprt  = (float*)((char*)d_ws + WS_BBLK_BYTES);  // reuse Bblk (dead after k_fused)

    k_prep  <<<dim3(2016),      dim3(256), 0, stream>>>(pd, sd, lbsw, Je9, Jh, Jreg, vt,
                                                        Bblk, W2, JallF, ws);
    k_batch <<<dim3(1024),      dim3(64),  0, stream>>>(betas, poses, ws, Ablk, A2, out);
    k_fused <<<dim3(108, 32),   dim3(256), 0, stream>>>(Ablk, Bblk, A2, W2, vt, out);
    k_jreg2 <<<dim3(32, NSEG),  dim3(256), 0, stream>>>(out, JallF, Pprt);
    k_tail  <<<dim3(444),       dim3(256), 0, stream>>>(Pprt, eidx, out);
}

// Round 17
// 103.500 us; speedup vs baseline: 1.1721x; 1.1721x over previous
//
#include <hip/hip_runtime.h>

#define VV 6890
#define N3 20670      // V*3
#define NVT 216       // ceil(N3/96) vertex tiles (32 verts each)
#define NKC 7         // K chunks of 32 (K=224)
#define NJOUT 61
#define OUTJ ((size_t)1024*VV*3)
#define NJCH 216      // ceil(VV/32) v-chunks for joint regression
#define NSEG 27       // split-K segments for joint regression (216 = 27*8)

// ws layout (bytes): JT f32[72]@0, JS f32[720]@288, JallF bf16 @4096 (432KB),
// Ablk bf16 @1183744, Bblk bf16 @1642496 (9.29MB; REUSED as jreg partials after
// k_fused), A2 @10932224, W2 @12505088 -> total 12947456 (proven footprint)
#define WS_JT 0
#define WS_JS 72
#define WS_JALL_BYTES 4096
#define WS_ABLK_BYTES 1183744
#define WS_BBLK_BYTES 1642496
#define WS_A2_BYTES   10932224
#define WS_W2_BYTES   12505088

typedef float f32x4 __attribute__((ext_vector_type(4)));
typedef short bf16x8 __attribute__((ext_vector_type(8)));

__constant__ int c_par[24] = {-1,0,0,0,1,2,3,4,5,6,7,8,9,9,9,12,13,14,16,17,18,19,20,21};

__device__ __forceinline__ short f2bf(float x) {
    union { float f; unsigned u; } v; v.f = x;
    unsigned r = (v.u + 0x7fffu + ((v.u >> 16) & 1u)) >> 16;
    return (short)r;
}
__device__ __forceinline__ float bf2f(short h) {
    union { unsigned u; float f; } v; v.u = ((unsigned)(unsigned short)h) << 16;
    return v.f;
}

// ---- K0: merged prep. bid<1512: buildB tile; <1944: W2/JallF frags; <2016: jointreg ----
__global__ __launch_bounds__(256) void k_prep(
    const float* __restrict__ pd, const float* __restrict__ sd,
    const float* __restrict__ lbsw, const float* __restrict__ Je9,
    const float* __restrict__ Jh, const float* __restrict__ Jreg,
    const float* __restrict__ vt,
    short* __restrict__ Bblk, short* __restrict__ W2, short* __restrict__ JallF,
    float* __restrict__ ws)
{
    const int bid = blockIdx.x;
    const int tid = threadIdx.x;
    __shared__ float T[32][97];

    if (bid < 1512) {
        const int nt = bid / 7, kc = bid % 7;
        for (int idx = tid; idx < 3072; idx += 256) {
            const int kl = idx / 96, c = idx % 96;
            const int kg = kc*32 + kl;
            const int n = nt*96 + c;
            float val = 0.f;
            if (n < N3) {
                if (kg < 207) val = pd[(size_t)kg*N3 + n];
                else if (kg < 217) val = sd[(size_t)(n/3)*30 + (n%3)*10 + (kg-207)];
            }
            T[kl][c] = val;
        }
        __syncthreads();
        short* tile = Bblk + (size_t)(nt*NKC + kc)*3072;
        for (int s = tid; s < 384; s += 256) {
            const int c = s >> 2;
            const int hi = (s & 3) ^ ((c >> 1) & 3);
            bf16x8 pk;
#pragma unroll
            for (int e = 0; e < 8; e++) pk[e] = f2bf(T[hi*8+e][c]);
            *(bf16x8*)(tile + s*8) = pk;
        }
    } else if (bid < 1944) {
        if (tid < 64) {
            const int l = tid;
            const int l15 = l & 15, l4 = l >> 4;
            const int sb = bid - 1512;
            if (sb < NVT) {
                const int nt = sb;
#pragma unroll
                for (int nh = 0; nh < 2; nh++) {
                    const int v = nt*32 + nh*16 + l15;
                    bf16x8 pk;
#pragma unroll
                    for (int q = 0; q < 8; q++) {
                        const int j = l4*8 + q;
                        float val = (j < 24 && v < VV) ? lbsw[(size_t)v*24 + j] : 0.f;
                        pk[q] = f2bf(val);
                    }
                    *(bf16x8*)(W2 + ((size_t)(nt*2 + nh)*512) + l*8) = pk;
                }
            } else {
                const int ch = sb - NVT;
#pragma unroll
                for (int jh = 0; jh < 2; jh++) {
                    const int j = jh*16 + l15;
                    bf16x8 pk;
#pragma unroll
                    for (int q = 0; q < 8; q++) {
                        const int v = ch*32 + l4*8 + q;
                        float val = 0.f;
                        if (j < 26 && v < VV)
                            val = (j < 9) ? Je9[(size_t)j*VV + v] : Jh[(size_t)(j-9)*VV + v];
                        pk[q] = f2bf(val);
                    }
                    *(bf16x8*)(JallF + ((size_t)ch*2 + jh)*512 + l*8) = pk;
                }
            }
        }
    } else {
        const int jb = bid - 1944;
        const int j = jb / 3, k = jb % 3;
        float acc[11];
#pragma unroll
        for (int i = 0; i < 11; i++) acc[i] = 0.f;
        for (int v = tid; v < VV; v += 256) {
            const float jr = Jreg[j*VV + v];
            acc[0] += jr * vt[v*3 + k];
            const float* s = sd + (size_t)v*30 + k*10;
#pragma unroll
            for (int l = 0; l < 10; l++) acc[1+l] += jr * s[l];
        }
#pragma unroll
        for (int off = 1; off < 64; off <<= 1)
#pragma unroll
            for (int i = 0; i < 11; i++) acc[i] += __shfl_xor(acc[i], off);
        const int wv = tid >> 6, ln = tid & 63;
        if (ln == 0)
#pragma unroll
            for (int i = 0; i < 11; i++) T[wv][i] = acc[i];
        __syncthreads();
        if (tid == 0) {
            ws[WS_JT + j*3 + k] = T[0][0]+T[1][0]+T[2][0]+T[3][0];
#pragma unroll
            for (int l = 0; l < 10; l++)
                ws[WS_JS + (j*3+k)*10 + l] = T[0][1+l]+T[1][1+l]+T[2][1+l]+T[3][1+l];
        }
    }
}

// ---- K1: rodrigues + chain + bf16 A-matrix + A2 hi/lo fragments + joints[0:24] ----
__global__ __launch_bounds__(64) void k_batch(
    const float* __restrict__ betas, const float* __restrict__ poses,
    float* __restrict__ ws, short* __restrict__ Ablk, short* __restrict__ A2,
    float* __restrict__ out)
{
    const int b = blockIdx.x, lane = threadIdx.x;
    __shared__ float R[24][9], Jr[24][3], RJ[24][3], G[24][12];
    if (lane < 24) {
        const int j = lane;
        const float x = poses[b*72 + j*3 + 0];
        const float y = poses[b*72 + j*3 + 1];
        const float z = poses[b*72 + j*3 + 2];
        const float xe = x + 1e-8f, ye = y + 1e-8f, ze = z + 1e-8f;
        const float ang = sqrtf(xe*xe + ye*ye + ze*ze);
        const float inv = 1.0f / ang;
        const float rx = x*inv, ry = y*inv, rz = z*inv;
        const float sn = sinf(ang), cs = cosf(ang);
        const float K[9] = {0.f,-rz,ry, rz,0.f,-rx, -ry,rx,0.f};
        float Rl[9];
#pragma unroll
        for (int r = 0; r < 3; r++)
#pragma unroll
            for (int c = 0; c < 3; c++) {
                float kk = 0.f;
#pragma unroll
                for (int m = 0; m < 3; m++) kk += K[r*3+m]*K[m*3+c];
                Rl[r*3+c] = ((r==c)?1.f:0.f) + sn*K[r*3+c] + (1.f-cs)*kk;
            }
#pragma unroll
        for (int e = 0; e < 9; e++) R[j][e] = Rl[e];
#pragma unroll
        for (int k = 0; k < 3; k++) {
            float a = ws[WS_JT + j*3 + k];
#pragma unroll
            for (int l = 0; l < 10; l++) a += betas[b*10 + l] * ws[WS_JS + (j*3+k)*10 + l];
            Jr[j][k] = a;
        }
    }
    __syncthreads();
    {
        const int r = b & 31, mt = b >> 5;
        const int sw = (r >> 1) & 3;
        for (int k = lane; k < 224; k += 64) {
            float val;
            if (k < 207) { const int j = k/9 + 1, e = k - (j-1)*9;
                           val = R[j][e] - ((e==0||e==4||e==8)?1.f:0.f); }
            else if (k < 217) val = betas[b*10 + (k-207)];
            else val = 0.f;
            const int kc = k >> 5, hi = (k >> 3) & 3;
            Ablk[(size_t)(mt*NKC + kc)*1024 + r*32 + ((hi ^ sw)*8) + (k & 7)] = f2bf(val);
        }
    }
    if (lane < 24) {
        const int j = lane, p = c_par[j];
#pragma unroll
        for (int k = 0; k < 3; k++) RJ[j][k] = (j == 0) ? Jr[0][k] : (Jr[j][k] - Jr[p][k]);
    }
    __syncthreads();
    if (lane < 12) {
        const int r = lane >> 2, c = lane & 3;
        G[0][lane] = (c < 3) ? R[0][r*3+c] : RJ[0][r];
    }
    __syncthreads();
    for (int i = 1; i < 24; i++) {
        float val = 0.f;
        if (lane < 12) {
            const int r = lane >> 2, c = lane & 3, p = c_par[i];
            if (c < 3)
                val = G[p][r*4+0]*R[i][0+c] + G[p][r*4+1]*R[i][3+c] + G[p][r*4+2]*R[i][6+c];
            else
                val = G[p][r*4+0]*RJ[i][0] + G[p][r*4+1]*RJ[i][1] + G[p][r*4+2]*RJ[i][2] + G[p][r*4+3];
        }
        __syncthreads();
        if (lane < 12) G[i][lane] = val;
        __syncthreads();
    }
    if (lane < 24)
#pragma unroll
        for (int k = 0; k < 3; k++)
            out[OUTJ + ((size_t)b*NJOUT + lane)*3 + k] = G[lane][k*4+3];
    const int bt = b >> 5, mh = (b >> 4) & 1, b15 = b & 15;
    short* A2t = A2 + (size_t)bt*12*2*2*512;
    for (int e = lane; e < 288; e += 64) {
        const int j = e / 12, rc = e % 12, r = rc >> 2, c = rc & 3;
        float val = G[j][rc];
        if (c == 3)
            val -= G[j][r*4+0]*Jr[j][0] + G[j][r*4+1]*Jr[j][1] + G[j][r*4+2]*Jr[j][2];
        const short vhi = f2bf(val);
        const short vlo = f2bf(val - bf2f(vhi));
        const int lf = (j >> 3)*16 + b15, q = j & 7;
        A2t[((rc*2 + 0)*2 + mh)*512 + lf*8 + q] = vhi;
        A2t[((rc*2 + 1)*2 + mh)*512 + lf*8 + q] = vlo;
    }
    for (int idx = lane; idx < 192; idx += 64) {
        const int rc = idx >> 4, spl = (idx >> 3) & 1, q = idx & 7;
        A2t[((rc*2 + spl)*2 + mh)*512 + (48 + b15)*8 + q] = 0;
    }
}

// ---- K2: FUSED (R12 math). vp/Tl16 OVERLAY: u pre-read into registers after
//      phase 2, vp region then reused for Tl16. LDS = 25088 -> 5-6 blocks/CU
//      (VGPR-capped at 5 via launch_bounds). Values bit-identical to R12. ----
__global__ __launch_bounds__(256, 5) void k_fused(
    const short* __restrict__ Ablk, const short* __restrict__ Bblk,
    const short* __restrict__ A2, const short* __restrict__ W2,
    const float* __restrict__ vt, float* __restrict__ out)
{
    const int nt = blockIdx.x, bt = blockIdx.y;
    const int tid = threadIdx.x;
    const int lane = tid & 63, wid = tid >> 6;
    const int wm = wid >> 1, wn = wid & 1;
    const int l15 = lane & 15, l4 = lane >> 4;

    __shared__ char SM[25088] __attribute__((aligned(16)));
    float* Tl16 = (float*)SM;             // [32 b][12 e][16 v] stride 196 = 25088 B
    float* vp   = (float*)SM;             // [32 b][132] = 16896 B (overlaid; disjoint in time)

    // ---- phase-3 operand fragments (issued early, consumed after phase 1) ----
    const int e_base = wid*3;
    bf16x8 a2f[3][2][2], w2f[2];
    {
        const short* A2t = A2 + (size_t)bt*12*2*2*512;
#pragma unroll
        for (int ee = 0; ee < 3; ee++)
#pragma unroll
            for (int mh = 0; mh < 2; mh++)
#pragma unroll
                for (int spl = 0; spl < 2; spl++)
                    a2f[ee][mh][spl] = *(const bf16x8*)(A2t + (((e_base+ee)*2 + spl)*2 + mh)*512 + lane*8);
#pragma unroll
        for (int nh = 0; nh < 2; nh++)
            w2f[nh] = *(const bf16x8*)(W2 + (size_t)(nt*2 + nh)*512 + lane*8);
    }

    // ---- phase 1: pose GEMM, fragments direct from global (no LDS, no barriers) ----
    f32x4 acc[3];
#pragma unroll
    for (int n = 0; n < 3; n++) acc[n] = (f32x4){0.f,0.f,0.f,0.f};
    const int ar = wm*16 + l15;
    const int aoff = ar*32 + ((l4 ^ ((ar >> 1) & 3)) * 8);
    int boff[3];
#pragma unroll
    for (int n = 0; n < 3; n++) {
        const int c = wn*48 + n*16 + l15;
        boff[n] = c*32 + ((l4 ^ ((c >> 1) & 3)) * 8);
    }
    const short* gA = Ablk + (size_t)bt*NKC*1024;
    const short* gB = Bblk + (size_t)nt*NKC*3072;

#pragma unroll
    for (int kc = 0; kc < NKC; kc++) {
        const bf16x8 af  = *(const bf16x8*)(gA + kc*1024 + aoff);
        const bf16x8 bf0 = *(const bf16x8*)(gB + kc*3072 + boff[0]);
        const bf16x8 bf1 = *(const bf16x8*)(gB + kc*3072 + boff[1]);
        const bf16x8 bf2 = *(const bf16x8*)(gB + kc*3072 + boff[2]);
        acc[0] = __builtin_amdgcn_mfma_f32_16x16x32_bf16(af, bf0, acc[0], 0, 0, 0);
        acc[1] = __builtin_amdgcn_mfma_f32_16x16x32_bf16(af, bf1, acc[1], 0, 0, 0);
        acc[2] = __builtin_amdgcn_mfma_f32_16x16x32_bf16(af, bf2, acc[2], 0, 0, 0);
    }

    // ---- phase 2: acc + v_template -> vp (stride 132) ----
#pragma unroll
    for (int n = 0; n < 3; n++) {
        const int cl = wn*48 + n*16 + l15;
        const int cg = nt*96 + cl;
        const float vtv = (cg < N3) ? vt[cg] : 0.f;
        const int vloc = cl / 3, kk = cl - vloc*3;
        const int b0 = wm*16 + l4*4;
#pragma unroll
        for (int rg = 0; rg < 4; rg++)
            vp[(b0+rg)*132 + vloc*4 + kk] = acc[n][rg] + vtv;
    }
    __syncthreads();                       // vp complete

    // ---- pre-read u into registers (vp dead afterwards) ----
    const int bl = tid >> 3, vq = tid & 7;
    float4 u[2][2];                        // [half][i]
#pragma unroll
    for (int half = 0; half < 2; half++)
#pragma unroll
        for (int i = 0; i < 2; i++)
            u[half][i] = *(const float4*)&vp[bl*132 + (half*16 + vq + 8*i)*4];
    __syncthreads();                       // all u reads done; vp region reusable

    // ---- phase 3: T = w*A via MFMA into registers (all 12 quads) ----
    f32x4 at[3][2][2];
#pragma unroll
    for (int ee = 0; ee < 3; ee++)
#pragma unroll
        for (int mh = 0; mh < 2; mh++)
#pragma unroll
            for (int nh = 0; nh < 2; nh++) {
                f32x4 t = (f32x4){0.f,0.f,0.f,0.f};
                t = __builtin_amdgcn_mfma_f32_16x16x32_bf16(a2f[ee][mh][0], w2f[nh], t, 0, 0, 0);
                t = __builtin_amdgcn_mfma_f32_16x16x32_bf16(a2f[ee][mh][1], w2f[nh], t, 0, 0, 0);
                at[ee][mh][nh] = t;
            }

    // ---- phase 4: per vert-half: store Tl16 [b][e][v] (overlays vp), barrier, consume ----
#pragma unroll
    for (int half = 0; half < 2; half++) {
#pragma unroll
        for (int ee = 0; ee < 3; ee++)
#pragma unroll
            for (int mh = 0; mh < 2; mh++) {
                const int brow = mh*16 + l4*4;
#pragma unroll
                for (int rg = 0; rg < 4; rg++)
                    Tl16[(brow+rg)*196 + (e_base+ee)*16 + l15] = at[ee][mh][half][rg];
            }
        __syncthreads();
        const int bg = bt*32 + bl;
#pragma unroll
        for (int i = 0; i < 2; i++) {
            const int v = vq + 8*i;
            const float4 uu = u[half][i];
            float t[12];
#pragma unroll
            for (int e = 0; e < 12; e++) t[e] = Tl16[bl*196 + e*16 + v];
            const float r0 = t[0]*uu.x + t[1]*uu.y + t[2]*uu.z  + t[3];
            const float r1 = t[4]*uu.x + t[5]*uu.y + t[6]*uu.z  + t[7];
            const float r2 = t[8]*uu.x + t[9]*uu.y + t[10]*uu.z + t[11];
            const int gv = nt*32 + half*16 + v;
            if (gv < VV) {
                const size_t base = (size_t)bg*N3 + (size_t)gv*3;
                out[base+0] = r0; out[base+1] = r1; out[base+2] = r2;
            }
        }
        if (half == 0) __syncthreads();    // Tl16 rewritten next half
    }
}

// ---- K3: joint regression split-K MFMA GEMM -> per-block partials (NO atomics) ----
__global__ __launch_bounds__(256) void k_jreg2(
    const float* __restrict__ vsrc, const short* __restrict__ JallF,
    float* __restrict__ P)
{
    const int bt = blockIdx.x, seg = blockIdx.y;   // grid (32, 27)
    const int tid = threadIdx.x;
    const int lane = tid & 63, wid = tid >> 6;
    const int jh = wid >> 1, nh = wid & 1;
    const int l15 = lane & 15, l4 = lane >> 4;

    f32x4 C[3];
#pragma unroll
    for (int k = 0; k < 3; k++) C[k] = (f32x4){0.f,0.f,0.f,0.f};

    const int rowb = bt*32 + nh*16 + l15;
    const float* vrow = vsrc + (size_t)rowb*N3;
    const int c0 = seg*8, c1 = c0 + 8;
    for (int ch = c0; ch < c1; ch++) {
        const float* p = vrow + ch*96 + l4*24;
        float2 g[12];
#pragma unroll
        for (int t = 0; t < 12; t++) g[t] = *(const float2*)(p + t*2);
        const bf16x8 af = *(const bf16x8*)(JallF + ((size_t)ch*2 + jh)*512 + lane*8);
#pragma unroll
        for (int k = 0; k < 3; k++) {
            bf16x8 bf;
#pragma unroll
            for (int q = 0; q < 8; q++) {
                const int e = q*3 + k;
                bf[q] = f2bf((e & 1) ? g[e>>1].y : g[e>>1].x);
            }
            C[k] = __builtin_amdgcn_mfma_f32_16x16x32_bf16(af, bf, C[k], 0, 0, 0);
        }
    }
    float* Pp = P + (size_t)(seg*32 + bt)*2496 + (nh*16 + l15)*78;
#pragma unroll
    for (int k = 0; k < 3; k++)
#pragma unroll
        for (int rg = 0; rg < 4; rg++) {
            const int j = jh*16 + l4*4 + rg;
            if (j < 26) Pp[j*3 + k] = C[k][rg];
        }
}

// ---- K4: reduce partials -> joints 35..60, and 11 gathered extra joints ----
__global__ __launch_bounds__(256) void k_tail(
    const float* __restrict__ P, const int* __restrict__ eidx, float* __restrict__ out)
{
    const int gid = blockIdx.x*256 + threadIdx.x;
    if (gid < 79872) {                       // 1024*78 jfin elements
        const int b = gid / 78, r = gid % 78;
        float s = 0.f;
#pragma unroll
        for (int seg = 0; seg < NSEG; seg++)
            s += P[(size_t)(seg*32 + (b >> 5))*2496 + (b & 31)*78 + r];
        out[OUTJ + (size_t)b*183 + 105 + r] = s;
    } else if (gid < 79872 + 33792) {        // 1024*33 extra elements
        const int idx = gid - 79872;
        const int b = idx / 33, r = idx % 33, j = r / 3, k = r % 3;
        out[OUTJ + ((size_t)b*NJOUT + 24 + j)*3 + k] =
            out[(size_t)b*N3 + (size_t)eidx[j]*3 + k];
    }
}

extern "C" void kernel_launch(void* const* d_in, const int* in_sizes, int n_in,
                              void* d_out, int out_size, void* d_ws, size_t ws_size,
                              hipStream_t stream) {
    const float* betas = (const float*)d_in[0];
    const float* poses = (const float*)d_in[1];
    const int*   eidx  = (const int*)  d_in[2];
    const float* vt    = (const float*)d_in[3];
    const float* sd    = (const float*)d_in[4];
    const float* pd    = (const float*)d_in[5];
    const float* Jreg  = (const float*)d_in[6];
    const float* lbsw  = (const float*)d_in[7];
    const float* Je9   = (const float*)d_in[8];
    const float* Jh    = (const float*)d_in[9];
    float* out = (float*)d_out;
    float* ws  = (float*)d_ws;
    short* JallF = (short*)((char*)d_ws + WS_JALL_BYTES);
    short* Ablk  = (short*)((char*)d_ws + WS_ABLK_BYTES);
    short* Bblk  = (short*)((char*)d_ws + WS_BBLK_BYTES);
    short* A2    = (short*)((char*)d_ws + WS_A2_BYTES);
    short* W2    = (short*)((char*)d_ws + WS_W2_BYTES);
    float* Pprt  = (float*)((char*)d_ws + WS_BBLK_BYTES);  // reuse Bblk (dead after k_fused)

    k_prep  <<<dim3(2016),      dim3(256), 0, stream>>>(pd, sd, lbsw, Je9, Jh, Jreg, vt,
                                                        Bblk, W2, JallF, ws);
    k_batch <<<dim3(1024),      dim3(64),  0, stream>>>(betas, poses, ws, Ablk, A2, out);
    k_fused <<<dim3(NVT, 32),   dim3(256), 0, stream>>>(Ablk, Bblk, A2, W2, vt, out);
    k_jreg2 <<<dim3(32, NSEG),  dim3(256), 0, stream>>>(out, JallF, Pprt);
    k_tail  <<<dim3(444),       dim3(256), 0, stream>>>(Pprt, eidx, out);
}

// Round 18
// 103.000 us; speedup vs baseline: 1.1777x; 1.0049x over previous
//
#include <hip/hip_runtime.h>

#define VV 6890
#define N3 20670      // V*3
#define NVT 216       // ceil(N3/96) vertex tiles (32 verts each)
#define NKC 7         // K chunks of 32 (K=224)
#define NJOUT 61
#define OUTJ ((size_t)1024*VV*3)
#define NJCH 216      // ceil(VV/32) v-chunks for joint regression
#define NSEG 27       // split-K segments for joint regression (216 = 27*8)

// ws layout (bytes): JT f32[72]@0, JS f32[720]@288, JallF bf16 @4096 (432KB),
// Ablk bf16 @1183744, Bblk bf16 @1642496 (9.29MB; REUSED as jreg partials after
// k_fused), A2 @10932224, W2 @12505088 -> total 12947456 (proven footprint)
#define WS_JT 0
#define WS_JS 72
#define WS_JALL_BYTES 4096
#define WS_ABLK_BYTES 1183744
#define WS_BBLK_BYTES 1642496
#define WS_A2_BYTES   10932224
#define WS_W2_BYTES   12505088

typedef float f32x4 __attribute__((ext_vector_type(4)));
typedef short bf16x8 __attribute__((ext_vector_type(8)));

__constant__ int c_par[24] = {-1,0,0,0,1,2,3,4,5,6,7,8,9,9,9,12,13,14,16,17,18,19,20,21};

__device__ __forceinline__ short f2bf(float x) {
    union { float f; unsigned u; } v; v.f = x;
    unsigned r = (v.u + 0x7fffu + ((v.u >> 16) & 1u)) >> 16;
    return (short)r;
}
__device__ __forceinline__ float bf2f(short h) {
    union { unsigned u; float f; } v; v.u = ((unsigned)(unsigned short)h) << 16;
    return v.f;
}

// ---- K0: merged prep. bid<1512: buildB tile; <1944: W2/JallF frags; <2016: jointreg ----
__global__ __launch_bounds__(256) void k_prep(
    const float* __restrict__ pd, const float* __restrict__ sd,
    const float* __restrict__ lbsw, const float* __restrict__ Je9,
    const float* __restrict__ Jh, const float* __restrict__ Jreg,
    const float* __restrict__ vt,
    short* __restrict__ Bblk, short* __restrict__ W2, short* __restrict__ JallF,
    float* __restrict__ ws)
{
    const int bid = blockIdx.x;
    const int tid = threadIdx.x;
    __shared__ float T[32][97];

    if (bid < 1512) {
        const int nt = bid / 7, kc = bid % 7;
        for (int idx = tid; idx < 3072; idx += 256) {
            const int kl = idx / 96, c = idx % 96;
            const int kg = kc*32 + kl;
            const int n = nt*96 + c;
            float val = 0.f;
            if (n < N3) {
                if (kg < 207) val = pd[(size_t)kg*N3 + n];
                else if (kg < 217) val = sd[(size_t)(n/3)*30 + (n%3)*10 + (kg-207)];
            }
            T[kl][c] = val;
        }
        __syncthreads();
        short* tile = Bblk + (size_t)(nt*NKC + kc)*3072;
        for (int s = tid; s < 384; s += 256) {
            const int c = s >> 2;
            const int hi = (s & 3) ^ ((c >> 1) & 3);
            bf16x8 pk;
#pragma unroll
            for (int e = 0; e < 8; e++) pk[e] = f2bf(T[hi*8+e][c]);
            *(bf16x8*)(tile + s*8) = pk;
        }
    } else if (bid < 1944) {
        if (tid < 64) {
            const int l = tid;
            const int l15 = l & 15, l4 = l >> 4;
            const int sb = bid - 1512;
            if (sb < NVT) {
                const int nt = sb;
#pragma unroll
                for (int nh = 0; nh < 2; nh++) {
                    const int v = nt*32 + nh*16 + l15;
                    bf16x8 pk;
#pragma unroll
                    for (int q = 0; q < 8; q++) {
                        const int j = l4*8 + q;
                        float val = (j < 24 && v < VV) ? lbsw[(size_t)v*24 + j] : 0.f;
                        pk[q] = f2bf(val);
                    }
                    *(bf16x8*)(W2 + ((size_t)(nt*2 + nh)*512) + l*8) = pk;
                }
            } else {
                const int ch = sb - NVT;
#pragma unroll
                for (int jh = 0; jh < 2; jh++) {
                    const int j = jh*16 + l15;
                    bf16x8 pk;
#pragma unroll
                    for (int q = 0; q < 8; q++) {
                        const int v = ch*32 + l4*8 + q;
                        float val = 0.f;
                        if (j < 26 && v < VV)
                            val = (j < 9) ? Je9[(size_t)j*VV + v] : Jh[(size_t)(j-9)*VV + v];
                        pk[q] = f2bf(val);
                    }
                    *(bf16x8*)(JallF + ((size_t)ch*2 + jh)*512 + l*8) = pk;
                }
            }
        }
    } else {
        const int jb = bid - 1944;
        const int j = jb / 3, k = jb % 3;
        float acc[11];
#pragma unroll
        for (int i = 0; i < 11; i++) acc[i] = 0.f;
        for (int v = tid; v < VV; v += 256) {
            const float jr = Jreg[j*VV + v];
            acc[0] += jr * vt[v*3 + k];
            const float* s = sd + (size_t)v*30 + k*10;
#pragma unroll
            for (int l = 0; l < 10; l++) acc[1+l] += jr * s[l];
        }
#pragma unroll
        for (int off = 1; off < 64; off <<= 1)
#pragma unroll
            for (int i = 0; i < 11; i++) acc[i] += __shfl_xor(acc[i], off);
        const int wv = tid >> 6, ln = tid & 63;
        if (ln == 0)
#pragma unroll
            for (int i = 0; i < 11; i++) T[wv][i] = acc[i];
        __syncthreads();
        if (tid == 0) {
            ws[WS_JT + j*3 + k] = T[0][0]+T[1][0]+T[2][0]+T[3][0];
#pragma unroll
            for (int l = 0; l < 10; l++)
                ws[WS_JS + (j*3+k)*10 + l] = T[0][1+l]+T[1][1+l]+T[2][1+l]+T[3][1+l];
        }
    }
}

// ---- K1: rodrigues + chain + bf16 A-matrix + A2 hi/lo fragments + joints[0:24] ----
__global__ __launch_bounds__(64) void k_batch(
    const float* __restrict__ betas, const float* __restrict__ poses,
    float* __restrict__ ws, short* __restrict__ Ablk, short* __restrict__ A2,
    float* __restrict__ out)
{
    const int b = blockIdx.x, lane = threadIdx.x;
    __shared__ float R[24][9], Jr[24][3], RJ[24][3], G[24][12];
    if (lane < 24) {
        const int j = lane;
        const float x = poses[b*72 + j*3 + 0];
        const float y = poses[b*72 + j*3 + 1];
        const float z = poses[b*72 + j*3 + 2];
        const float xe = x + 1e-8f, ye = y + 1e-8f, ze = z + 1e-8f;
        const float ang = sqrtf(xe*xe + ye*ye + ze*ze);
        const float inv = 1.0f / ang;
        const float rx = x*inv, ry = y*inv, rz = z*inv;
        const float sn = sinf(ang), cs = cosf(ang);
        const float K[9] = {0.f,-rz,ry, rz,0.f,-rx, -ry,rx,0.f};
        float Rl[9];
#pragma unroll
        for (int r = 0; r < 3; r++)
#pragma unroll
            for (int c = 0; c < 3; c++) {
                float kk = 0.f;
#pragma unroll
                for (int m = 0; m < 3; m++) kk += K[r*3+m]*K[m*3+c];
                Rl[r*3+c] = ((r==c)?1.f:0.f) + sn*K[r*3+c] + (1.f-cs)*kk;
            }
#pragma unroll
        for (int e = 0; e < 9; e++) R[j][e] = Rl[e];
#pragma unroll
        for (int k = 0; k < 3; k++) {
            float a = ws[WS_JT + j*3 + k];
#pragma unroll
            for (int l = 0; l < 10; l++) a += betas[b*10 + l] * ws[WS_JS + (j*3+k)*10 + l];
            Jr[j][k] = a;
        }
    }
    __syncthreads();
    {
        const int r = b & 31, mt = b >> 5;
        const int sw = (r >> 1) & 3;
        for (int k = lane; k < 224; k += 64) {
            float val;
            if (k < 207) { const int j = k/9 + 1, e = k - (j-1)*9;
                           val = R[j][e] - ((e==0||e==4||e==8)?1.f:0.f); }
            else if (k < 217) val = betas[b*10 + (k-207)];
            else val = 0.f;
            const int kc = k >> 5, hi = (k >> 3) & 3;
            Ablk[(size_t)(mt*NKC + kc)*1024 + r*32 + ((hi ^ sw)*8) + (k & 7)] = f2bf(val);
        }
    }
    if (lane < 24) {
        const int j = lane, p = c_par[j];
#pragma unroll
        for (int k = 0; k < 3; k++) RJ[j][k] = (j == 0) ? Jr[0][k] : (Jr[j][k] - Jr[p][k]);
    }
    __syncthreads();
    if (lane < 12) {
        const int r = lane >> 2, c = lane & 3;
        G[0][lane] = (c < 3) ? R[0][r*3+c] : RJ[0][r];
    }
    __syncthreads();
    for (int i = 1; i < 24; i++) {
        float val = 0.f;
        if (lane < 12) {
            const int r = lane >> 2, c = lane & 3, p = c_par[i];
            if (c < 3)
                val = G[p][r*4+0]*R[i][0+c] + G[p][r*4+1]*R[i][3+c] + G[p][r*4+2]*R[i][6+c];
            else
                val = G[p][r*4+0]*RJ[i][0] + G[p][r*4+1]*RJ[i][1] + G[p][r*4+2]*RJ[i][2] + G[p][r*4+3];
        }
        __syncthreads();
        if (lane < 12) G[i][lane] = val;
        __syncthreads();
    }
    if (lane < 24)
#pragma unroll
        for (int k = 0; k < 3; k++)
            out[OUTJ + ((size_t)b*NJOUT + lane)*3 + k] = G[lane][k*4+3];
    const int bt = b >> 5, mh = (b >> 4) & 1, b15 = b & 15;
    short* A2t = A2 + (size_t)bt*12*2*2*512;
    for (int e = lane; e < 288; e += 64) {
        const int j = e / 12, rc = e % 12, r = rc >> 2, c = rc & 3;
        float val = G[j][rc];
        if (c == 3)
            val -= G[j][r*4+0]*Jr[j][0] + G[j][r*4+1]*Jr[j][1] + G[j][r*4+2]*Jr[j][2];
        const short vhi = f2bf(val);
        const short vlo = f2bf(val - bf2f(vhi));
        const int lf = (j >> 3)*16 + b15, q = j & 7;
        A2t[((rc*2 + 0)*2 + mh)*512 + lf*8 + q] = vhi;
        A2t[((rc*2 + 1)*2 + mh)*512 + lf*8 + q] = vlo;
    }
    for (int idx = lane; idx < 192; idx += 64) {
        const int rc = idx >> 4, spl = (idx >> 3) & 1, q = idx & 7;
        A2t[((rc*2 + spl)*2 + mh)*512 + (48 + b15)*8 + q] = 0;
    }
}

// ---- K2: FUSED (R17 structure). vp/Tl16 overlay, u pre-read to registers,
//      float3 (dwordx3) verts stores. LDS 25088 -> 5 blocks/CU. ----
__global__ __launch_bounds__(256, 5) void k_fused(
    const short* __restrict__ Ablk, const short* __restrict__ Bblk,
    const short* __restrict__ A2, const short* __restrict__ W2,
    const float* __restrict__ vt, float* __restrict__ out)
{
    const int nt = blockIdx.x, bt = blockIdx.y;
    const int tid = threadIdx.x;
    const int lane = tid & 63, wid = tid >> 6;
    const int wm = wid >> 1, wn = wid & 1;
    const int l15 = lane & 15, l4 = lane >> 4;

    __shared__ char SM[25088] __attribute__((aligned(16)));
    float* Tl16 = (float*)SM;             // [32 b][12 e][16 v] stride 196 = 25088 B
    float* vp   = (float*)SM;             // [32 b][132] = 16896 B (overlaid; disjoint in time)

    // ---- phase-3 operand fragments (issued early, consumed after phase 1) ----
    const int e_base = wid*3;
    bf16x8 a2f[3][2][2], w2f[2];
    {
        const short* A2t = A2 + (size_t)bt*12*2*2*512;
#pragma unroll
        for (int ee = 0; ee < 3; ee++)
#pragma unroll
            for (int mh = 0; mh < 2; mh++)
#pragma unroll
                for (int spl = 0; spl < 2; spl++)
                    a2f[ee][mh][spl] = *(const bf16x8*)(A2t + (((e_base+ee)*2 + spl)*2 + mh)*512 + lane*8);
#pragma unroll
        for (int nh = 0; nh < 2; nh++)
            w2f[nh] = *(const bf16x8*)(W2 + (size_t)(nt*2 + nh)*512 + lane*8);
    }

    // ---- phase 1: pose GEMM, fragments direct from global (no LDS, no barriers) ----
    f32x4 acc[3];
#pragma unroll
    for (int n = 0; n < 3; n++) acc[n] = (f32x4){0.f,0.f,0.f,0.f};
    const int ar = wm*16 + l15;
    const int aoff = ar*32 + ((l4 ^ ((ar >> 1) & 3)) * 8);
    int boff[3];
#pragma unroll
    for (int n = 0; n < 3; n++) {
        const int c = wn*48 + n*16 + l15;
        boff[n] = c*32 + ((l4 ^ ((c >> 1) & 3)) * 8);
    }
    const short* gA = Ablk + (size_t)bt*NKC*1024;
    const short* gB = Bblk + (size_t)nt*NKC*3072;

#pragma unroll
    for (int kc = 0; kc < NKC; kc++) {
        const bf16x8 af  = *(const bf16x8*)(gA + kc*1024 + aoff);
        const bf16x8 bf0 = *(const bf16x8*)(gB + kc*3072 + boff[0]);
        const bf16x8 bf1 = *(const bf16x8*)(gB + kc*3072 + boff[1]);
        const bf16x8 bf2 = *(const bf16x8*)(gB + kc*3072 + boff[2]);
        acc[0] = __builtin_amdgcn_mfma_f32_16x16x32_bf16(af, bf0, acc[0], 0, 0, 0);
        acc[1] = __builtin_amdgcn_mfma_f32_16x16x32_bf16(af, bf1, acc[1], 0, 0, 0);
        acc[2] = __builtin_amdgcn_mfma_f32_16x16x32_bf16(af, bf2, acc[2], 0, 0, 0);
    }

    // ---- phase 2: acc + v_template -> vp (stride 132) ----
#pragma unroll
    for (int n = 0; n < 3; n++) {
        const int cl = wn*48 + n*16 + l15;
        const int cg = nt*96 + cl;
        const float vtv = (cg < N3) ? vt[cg] : 0.f;
        const int vloc = cl / 3, kk = cl - vloc*3;
        const int b0 = wm*16 + l4*4;
#pragma unroll
        for (int rg = 0; rg < 4; rg++)
            vp[(b0+rg)*132 + vloc*4 + kk] = acc[n][rg] + vtv;
    }
    __syncthreads();                       // vp complete

    // ---- pre-read u into registers (vp dead afterwards) ----
    const int bl = tid >> 3, vq = tid & 7;
    float4 u[2][2];                        // [half][i]
#pragma unroll
    for (int half = 0; half < 2; half++)
#pragma unroll
        for (int i = 0; i < 2; i++)
            u[half][i] = *(const float4*)&vp[bl*132 + (half*16 + vq + 8*i)*4];
    __syncthreads();                       // all u reads done; vp region reusable

    // ---- phase 3: T = w*A via MFMA into registers (all 12 quads) ----
    f32x4 at[3][2][2];
#pragma unroll
    for (int ee = 0; ee < 3; ee++)
#pragma unroll
        for (int mh = 0; mh < 2; mh++)
#pragma unroll
            for (int nh = 0; nh < 2; nh++) {
                f32x4 t = (f32x4){0.f,0.f,0.f,0.f};
                t = __builtin_amdgcn_mfma_f32_16x16x32_bf16(a2f[ee][mh][0], w2f[nh], t, 0, 0, 0);
                t = __builtin_amdgcn_mfma_f32_16x16x32_bf16(a2f[ee][mh][1], w2f[nh], t, 0, 0, 0);
                at[ee][mh][nh] = t;
            }

    // ---- phase 4: per vert-half: store Tl16 [b][e][v] (overlays vp), barrier, consume ----
#pragma unroll
    for (int half = 0; half < 2; half++) {
#pragma unroll
        for (int ee = 0; ee < 3; ee++)
#pragma unroll
            for (int mh = 0; mh < 2; mh++) {
                const int brow = mh*16 + l4*4;
#pragma unroll
                for (int rg = 0; rg < 4; rg++)
                    Tl16[(brow+rg)*196 + (e_base+ee)*16 + l15] = at[ee][mh][half][rg];
            }
        __syncthreads();
        const int bg = bt*32 + bl;
#pragma unroll
        for (int i = 0; i < 2; i++) {
            const int v = vq + 8*i;
            const float4 uu = u[half][i];
            float t[12];
#pragma unroll
            for (int e = 0; e < 12; e++) t[e] = Tl16[bl*196 + e*16 + v];
            const float r0 = t[0]*uu.x + t[1]*uu.y + t[2]*uu.z  + t[3];
            const float r1 = t[4]*uu.x + t[5]*uu.y + t[6]*uu.z  + t[7];
            const float r2 = t[8]*uu.x + t[9]*uu.y + t[10]*uu.z + t[11];
            const int gv = nt*32 + half*16 + v;
            if (gv < VV) {
                float3* p = (float3*)(out + (size_t)bg*N3 + (size_t)gv*3);
                *p = (float3){r0, r1, r2};   // global_store_dwordx3
            }
        }
        if (half == 0) __syncthreads();    // Tl16 rewritten next half
    }
}

// ---- K3: joint regression split-K MFMA GEMM -> per-block partials (NO atomics) ----
__global__ __launch_bounds__(256) void k_jreg2(
    const float* __restrict__ vsrc, const short* __restrict__ JallF,
    float* __restrict__ P)
{
    const int bt = blockIdx.x, seg = blockIdx.y;   // grid (32, 27)
    const int tid = threadIdx.x;
    const int lane = tid & 63, wid = tid >> 6;
    const int jh = wid >> 1, nh = wid & 1;
    const int l15 = lane & 15, l4 = lane >> 4;

    f32x4 C[3];
#pragma unroll
    for (int k = 0; k < 3; k++) C[k] = (f32x4){0.f,0.f,0.f,0.f};

    const int rowb = bt*32 + nh*16 + l15;
    const float* vrow = vsrc + (size_t)rowb*N3;
    const int c0 = seg*8, c1 = c0 + 8;
    for (int ch = c0; ch < c1; ch++) {
        const float* p = vrow + ch*96 + l4*24;
        float2 g[12];
#pragma unroll
        for (int t = 0; t < 12; t++) g[t] = *(const float2*)(p + t*2);
        const bf16x8 af = *(const bf16x8*)(JallF + ((size_t)ch*2 + jh)*512 + lane*8);
#pragma unroll
        for (int k = 0; k < 3; k++) {
            bf16x8 bf;
#pragma unroll
            for (int q = 0; q < 8; q++) {
                const int e = q*3 + k;
                bf[q] = f2bf((e & 1) ? g[e>>1].y : g[e>>1].x);
            }
            C[k] = __builtin_amdgcn_mfma_f32_16x16x32_bf16(af, bf, C[k], 0, 0, 0);
        }
    }
    float* Pp = P + (size_t)(seg*32 + bt)*2496 + (nh*16 + l15)*78;
#pragma unroll
    for (int k = 0; k < 3; k++)
#pragma unroll
        for (int rg = 0; rg < 4; rg++) {
            const int j = jh*16 + l4*4 + rg;
            if (j < 26) Pp[j*3 + k] = C[k][rg];
        }
}

// ---- K4: reduce partials -> joints 35..60, and 11 gathered extra joints ----
__global__ __launch_bounds__(256) void k_tail(
    const float* __restrict__ P, const int* __restrict__ eidx, float* __restrict__ out)
{
    const int gid = blockIdx.x*256 + threadIdx.x;
    if (gid < 79872) {                       // 1024*78 jfin elements
        const int b = gid / 78, r = gid % 78;
        float s = 0.f;
#pragma unroll
        for (int seg = 0; seg < NSEG; seg++)
            s += P[(size_t)(seg*32 + (b >> 5))*2496 + (b & 31)*78 + r];
        out[OUTJ + (size_t)b*183 + 105 + r] = s;
    } else if (gid < 79872 + 33792) {        // 1024*33 extra elements
        const int idx = gid - 79872;
        const int b = idx / 33, r = idx % 33, j = r / 3, k = r % 3;
        out[OUTJ + ((size_t)b*NJOUT + 24 + j)*3 + k] =
            out[(size_t)b*N3 + (size_t)eidx[j]*3 + k];
    }
}

extern "C" void kernel_launch(void* const* d_in, const int* in_sizes, int n_in,
                              void* d_out, int out_size, void* d_ws, size_t ws_size,
                              hipStream_t stream) {
    const float* betas = (const float*)d_in[0];
    const float* poses = (const float*)d_in[1];
    const int*   eidx  = (const int*)  d_in[2];
    const float* vt    = (const float*)d_in[3];
    const float* sd    = (const float*)d_in[4];
    const float* pd    = (const float*)d_in[5];
    const float* Jreg  = (const float*)d_in[6];
    const float* lbsw  = (const float*)d_in[7];
    const float* Je9   = (const float*)d_in[8];
    const float* Jh    = (const float*)d_in[9];
    float* out = (float*)d_out;
    float* ws  = (float*)d_ws;
    short* JallF = (short*)((char*)d_ws + WS_JALL_BYTES);
    short* Ablk  = (short*)((char*)d_ws + WS_ABLK_BYTES);
    short* Bblk  = (short*)((char*)d_ws + WS_BBLK_BYTES);
    short* A2    = (short*)((char*)d_ws + WS_A2_BYTES);
    short* W2    = (short*)((char*)d_ws + WS_W2_BYTES);
    float* Pprt  = (float*)((char*)d_ws + WS_BBLK_BYTES);  // reuse Bblk (dead after k_fused)

    k_prep  <<<dim3(2016),      dim3(256), 0, stream>>>(pd, sd, lbsw, Je9, Jh, Jreg, vt,
                                                        Bblk, W2, JallF, ws);
    k_batch <<<dim3(1024),      dim3(64),  0, stream>>>(betas, poses, ws, Ablk, A2, out);
    k_fused <<<dim3(NVT, 32),   dim3(256), 0, stream>>>(Ablk, Bblk, A2, W2, vt, out);
    k_jreg2 <<<dim3(32, NSEG),  dim3(256), 0, stream>>>(out, JallF, Pprt);
    k_tail  <<<dim3(444),       dim3(256), 0, stream>>>(Pprt, eidx, out);
}